// Round 15
// baseline (135.058 us; speedup 1.0000x reference)
//
#include <hip/hip_runtime.h>

typedef unsigned short u16;
typedef unsigned int u32;
typedef __attribute__((ext_vector_type(8))) short bf16x8;
typedef __attribute__((ext_vector_type(4))) short bf16x4;
typedef __attribute__((ext_vector_type(4))) float f32x4;

#define MFMA(a, b, c) __builtin_amdgcn_mfma_f32_16x16x32_bf16((a), (b), (c), 0, 0, 0)
#define MFMA16(a, b, c) __builtin_amdgcn_mfma_f32_16x16x16bf16_1k((a), (b), (c), 0, 0, 0)

#define LOG2E 1.442695041f

// bare v_exp_f32: computes 2^x (pure, schedulable)
static __device__ __forceinline__ float ex2(float x) {
  float r;
  asm("v_exp_f32 %0, %1" : "=v"(r) : "v"(x));
  return r;
}

// round-to-nearest-even f32 -> bf16
static __device__ __forceinline__ u16 f2bf(float x) {
  u32 u = __float_as_uint(x);
  u += 0x7FFFu + ((u >> 16) & 1u);
  return (u16)(u >> 16);
}
// pack two f32 -> (bf16(hi)<<16)|bf16(lo), truncating (hot paths)
static __device__ __forceinline__ u32 packbf_t(float hi, float lo) {
  return __builtin_amdgcn_perm(__float_as_uint(hi), __float_as_uint(lo), 0x07060302u);
}
// rounded pack: lo | hi<<16
static __device__ __forceinline__ u32 packbf(float lo, float hi) {
  return (u32)f2bf(lo) | ((u32)f2bf(hi) << 16);
}

// ---------------------------------------------------------------------------
// Kernel 1: 1x1-conv projections, ONE projection per block (z 0..4):
// z0: Q + hbuf, z1: Kh, z2: Vh, z3: Km, z4: Vm. grid (16,16,5) = 1280 blocks.
// Inline f32->bf16 weight conversion (weights L2-broadcast). Q weights/bias
// pre-scaled by log2e so attention uses bare v_exp_f32 (exp2). Folded
// tail-weight prep (Wzb/Wmb/bmp) with gate-wise log2e scaling (mg rows get
// 2*log2e for tanh); ordering guaranteed by kernel boundary.
// Q/K: (B,N,64). V: BLOCKED (b, kc=n/64, kw=key16grp, c, key16).
// ---------------------------------------------------------------------------
__global__ __launch_bounds__(256) void proj_kernel(
    const float* __restrict__ h, const float* __restrict__ m_,
    const float* __restrict__ bq, const float* __restrict__ bk,
    const float* __restrict__ bk2, const float* __restrict__ bv,
    const float* __restrict__ bv2,
    const float* __restrict__ Wq, const float* __restrict__ Wk,
    const float* __restrict__ Wk2, const float* __restrict__ Wv,
    const float* __restrict__ Wv2,
    const float* __restrict__ Wz, const float* __restrict__ Wm,
    const float* __restrict__ bm,
    u16* __restrict__ Qb, u16* __restrict__ Khb, u16* __restrict__ Kmb,
    u16* __restrict__ Vhb, u16* __restrict__ Vmb, u16* __restrict__ hbuf,
    u16* __restrict__ Wzb, u16* __restrict__ Wmb, float* __restrict__ bmp)
{
  const int tid = threadIdx.x;
  const int b = blockIdx.y, n0 = blockIdx.x * 64, z = blockIdx.z;

  // ---- folded tail-weight prep (consumed by merged kernel, next launch)
  {
    const int gid = (blockIdx.z * 256 + blockIdx.y * 16 + blockIdx.x) * 256 + tid;
    if (gid < 16384) {
      Wzb[gid] = f2bf(Wz[gid]);
    } else if (gid < 53248) {
      const int e = gid - 16384;
      const int p = e / 192, k = e % 192;
      const int hb2 = p / 96, r1 = p % 96, ctl = r1 / 48, r2 = r1 % 48;
      const int g = r2 >> 4, mm = r2 & 15;
      const int o = g * 64 + (hb2 * 2 + ctl) * 16 + mm;
      const float scl = (g == 1) ? 2.f * LOG2E : LOG2E;  // mg: tanh via 2^(2x)
      Wmb[p * 192 + k] = f2bf(Wm[o * 192 + k] * scl);
    } else if (gid < 53440) {
      const int p = gid - 53248;
      const int hb2 = p / 96, r1 = p % 96, ctl = r1 / 48, r2 = r1 % 48;
      const int g = r2 >> 4, mm = r2 & 15;
      const int o = g * 64 + (hb2 * 2 + ctl) * 16 + mm;
      const float scl = (g == 1) ? 2.f * LOG2E : LOG2E;
      bmp[p] = bm[o] * scl;
    }
  }

  __shared__ __align__(16) u16 xt[64][72];  // [px][c] bf16
  const float* __restrict__ X = (z >= 3) ? m_ : h;

  {
    const int px = tid & 63, c0 = (tid >> 6) * 16;
#pragma unroll
    for (int i = 0; i < 8; ++i) {
      const int c = c0 + 2 * i;
      const float f0 = X[(b * 64 + c) * 1024 + n0 + px];
      const float f1 = X[(b * 64 + c + 1) * 1024 + n0 + px];
      *(u32*)&xt[px][c] = packbf(f0, f1);
    }
  }
  __syncthreads();

  const int lane = tid & 63, w = tid >> 6;  // w = 16-px tile
  const int mm = lane & 15, q = lane >> 4;

  const bf16x8 xa0 = *(const bf16x8*)&xt[w * 16 + mm][q * 8];
  const bf16x8 xa1 = *(const bf16x8*)&xt[w * 16 + mm][32 + q * 8];

  // load row `row` cols col0..col0+7 of a 64-wide f32 matrix, scaled, as bf16x8
  auto ldw8 = [&](const float* Wf, int row, int col0, float scl) {
    const float4 a = *(const float4*)(Wf + row * 64 + col0);
    const float4 bb = *(const float4*)(Wf + row * 64 + col0 + 4);
    union { u32 u[4]; bf16x8 v; } r;
    r.u[0] = packbf(a.x * scl, a.y * scl);
    r.u[1] = packbf(a.z * scl, a.w * scl);
    r.u[2] = packbf(bb.x * scl, bb.y * scl);
    r.u[3] = packbf(bb.z * scl, bb.w * scl);
    return r.v;
  };

  auto qk_store = [&](u16* dst, const float* Wf, const float* bias, float scl) {
#pragma unroll
    for (int ot = 0; ot < 4; ++ot) {
      const bf16x8 wb0 = ldw8(Wf, ot * 16 + mm, q * 8, scl);
      const bf16x8 wb1 = ldw8(Wf, ot * 16 + mm, 32 + q * 8, scl);
      const float4 b4 = *(const float4*)(bias + ot * 16 + q * 4);
      f32x4 d = {b4.x * scl, b4.y * scl, b4.z * scl, b4.w * scl};
      d = MFMA(wb0, xa0, d);
      d = MFMA(wb1, xa1, d);
      uint2 val;
      val.x = packbf(d[0], d[1]);
      val.y = packbf(d[2], d[3]);
      *(uint2*)(dst + (b * 1024 + n0 + w * 16 + mm) * 64 + ot * 16 + q * 4) = val;
    }
  };
  // V store, layout (b, kc, kw, c, k16): key = w*16 + (q*4+r)
  auto v_store = [&](u16* dst, const float* Wf, const float* bias) {
#pragma unroll
    for (int ot = 0; ot < 4; ++ot) {
      const bf16x8 wb0 = ldw8(Wf, ot * 16 + mm, q * 8, 1.f);
      const bf16x8 wb1 = ldw8(Wf, ot * 16 + mm, 32 + q * 8, 1.f);
      const float bb = bias[ot * 16 + mm];
      f32x4 d = {bb, bb, bb, bb};
      d = MFMA(xa0, wb0, d);
      d = MFMA(xa1, wb1, d);
      uint2 val;
      val.x = packbf(d[0], d[1]);
      val.y = packbf(d[2], d[3]);
      *(uint2*)(dst + b * 65536 + blockIdx.x * 4096 + w * 1024 +
                (ot * 16 + mm) * 16 + q * 4) = val;
    }
  };

  if (z == 0) {
    qk_store(Qb, Wq, bq, LOG2E);   // Q pre-scaled: attn exp uses bare 2^x
    const int px = tid >> 2, sg = tid & 3;
    u32* dst = (u32*)(hbuf + (b * 1024 + n0 + px) * 64 + sg * 16);
    const u16* srcr = &xt[px][sg * 16];
#pragma unroll
    for (int j = 0; j < 8; ++j) dst[j] = *(const u32*)(srcr + 2 * j);
  } else if (z == 1) {
    qk_store(Khb, Wk, bk, 1.f);
  } else if (z == 2) {
    v_store(Vhb, Wv, bv);
  } else if (z == 3) {
    qk_store(Kmb, Wk2, bk2, 1.f);
  } else {
    v_store(Vmb, Wv2, bv2);
  }
}

// ---------------------------------------------------------------------------
// Kernel 2: MERGED attention + tail with DUAL-BRANCH INTERLEAVED loop.
// 512 blocks = 16 b (XCD-affine) x 32 query-groups of 32 queries; 2/CU.
// compute_both: both branches' LDS fragments read as ONE cluster (single
// lgkm wait region), then two independent QK->exp2->PV chains per qt for
// the scheduler to interleave. exp link shortened to bare v_exp_f32 (Q
// pre-scaled by log2e in proj). Per-wave single-buffered arenas (H, M);
// WAR-safe by same-wave DS ordering. Then combine -> zproj -> final -> gates.
// ---------------------------------------------------------------------------
__global__ __launch_bounds__(256) void attn_tail_kernel(
    const u16* __restrict__ Qb, const u16* __restrict__ Khb,
    const u16* __restrict__ Kmb, const u16* __restrict__ Vhb,
    const u16* __restrict__ Vmb, const u16* __restrict__ hbuf,
    const float* __restrict__ m_, const u16* __restrict__ Wzb,
    const float* __restrict__ bz, const u16* __restrict__ Wmb,
    const float* __restrict__ bmp, float* __restrict__ out)
{
  const int id = blockIdx.x;
  const int b = id & 15;            // batch -> fixed XCD
  const int qg = id >> 4;           // 0..31
  const int q0 = qg * 32;

  const u16* __restrict__ Kh = Khb + b * 65536;  // (N,64)
  const u16* __restrict__ Vh = Vhb + b * 65536;  // (kc,kw,c,16)
  const u16* __restrict__ Km = Kmb + b * 65536;
  const u16* __restrict__ Vm = Vmb + b * 65536;

  __shared__ __align__(16) u16 pool[21504];   // 4 wave-arenas / zcb / zp2
  __shared__ __align__(16) u16 zp[32][136];   // combined normalized Z tile
  __shared__ float rsw[4][32];

  const int tid = threadIdx.x, w = tid >> 6, lane = tid & 63;
  const int mm = lane & 15, q = lane >> 4;

  u16* const arenaH = pool + w * 5376;        // Kt 1152 + Vt 1536
  u16* const arenaM = arenaH + 2688;

  // Q B-operand frags for 2 query tiles: B[n=query=mm][k=d=q*8+j]
  bf16x8 qb0[2], qb1[2];
#pragma unroll
  for (int qt = 0; qt < 2; ++qt) {
    const u16* Qp = Qb + (b * 1024 + q0 + qt * 16 + mm) * 64;
    qb0[qt] = *(const bf16x8*)(Qp + q * 8);
    qb1[qt] = *(const bf16x8*)(Qp + 32 + q * 8);
  }

  f32x4 zA[2][4], zB[2][4];
  float rpA[2] = {0.f, 0.f}, rpB[2] = {0.f, 0.f};
#pragma unroll
  for (int qt = 0; qt < 2; ++qt)
#pragma unroll
    for (int ct = 0; ct < 4; ++ct) {
      zA[qt][ct] = (f32x4){0.f, 0.f, 0.f, 0.f};
      zB[qt][ct] = (f32x4){0.f, 0.f, 0.f, 0.f};
    }

  // per-wave staging: K slice (16 keys x 64d = 2KB) and V slice (64c x 16k =
  // 2KB) contiguous; each lane loads 32 B of each. Two live reg sets (H, M).
  uint4 kh0, kh1, vh0, vh1, km0, km1, vm0, vm1;
  auto ldg = [&](const u16* K, const u16* V, int kc, uint4& r0, uint4& r1,
                 uint4& s0, uint4& s1) {
    const u16* Ks = K + kc * 4096 + w * 1024 + lane * 16;
    const u16* Vs = V + kc * 4096 + w * 1024 + lane * 16;
    r0 = *(const uint4*)Ks;
    r1 = *(const uint4*)(Ks + 8);
    s0 = *(const uint4*)Vs;
    s1 = *(const uint4*)(Vs + 8);
  };
  auto stl = [&](u16* arena, const uint4& r0, const uint4& r1, const uint4& s0,
                 const uint4& s1) {
    u16* Kd = arena + (lane >> 2) * 72 + (lane & 3) * 16;
    u16* Vd = arena + 1152 + lane * 24;
    *(uint4*)Kd = r0;
    *(uint4*)(Kd + 8) = r1;
    *(uint4*)Vd = s0;
    *(uint4*)(Vd + 8) = s1;
  };

  // one qt-chain step: QK (MFMA) -> exp2 -> pack -> PV (4x MFMA16)
  auto chain = [&](const bf16x8& kf0, const bf16x8& kf1, const bf16x4* vf,
                   int qt, f32x4 (&z)[2][4], float (&rp)[2]) {
    f32x4 s = {0.f, 0.f, 0.f, 0.f};
    s = MFMA(kf0, qb0[qt], s);
    s = MFMA(kf1, qb1[qt], s);
    const float e0 = ex2(s[0]), e1 = ex2(s[1]);
    const float e2 = ex2(s[2]), e3 = ex2(s[3]);
    rp[qt] += (e0 + e1) + (e2 + e3);
    union { u32 u[2]; bf16x4 v; } pb;
    pb.u[0] = packbf_t(e1, e0);   // B[k=q*4+{0,1}][n=mm]
    pb.u[1] = packbf_t(e3, e2);   // B[k=q*4+{2,3}][n=mm]
#pragma unroll
    for (int ct = 0; ct < 4; ++ct) z[qt][ct] = MFMA16(vf[ct], pb.v, z[qt][ct]);
  };

  auto compute_both = [&]() {
    // batch ALL fragment reads (both branches) into one ds_read cluster
    const bf16x8 kfH0 = *(const bf16x8*)(arenaH + mm * 72 + q * 8);
    const bf16x8 kfH1 = *(const bf16x8*)(arenaH + mm * 72 + 32 + q * 8);
    const bf16x8 kfM0 = *(const bf16x8*)(arenaM + mm * 72 + q * 8);
    const bf16x8 kfM1 = *(const bf16x8*)(arenaM + mm * 72 + 32 + q * 8);
    bf16x4 vfH[4], vfM[4];
#pragma unroll
    for (int ct = 0; ct < 4; ++ct) {
      vfH[ct] = *(const bf16x4*)(arenaH + 1152 + (ct * 16 + mm) * 24 + q * 4);
      vfM[ct] = *(const bf16x4*)(arenaM + 1152 + (ct * 16 + mm) * 24 + q * 4);
    }
    // 4 independent chains (2 qt x 2 branches) for the scheduler
    chain(kfH0, kfH1, vfH, 0, zA, rpA);
    chain(kfM0, kfM1, vfM, 0, zB, rpB);
    chain(kfH0, kfH1, vfH, 1, zA, rpA);
    chain(kfM0, kfM1, vfM, 1, zB, rpB);
  };

  // prologue: chunk0 -> both arenas; regs hold chunk1 for both branches
  ldg(Kh, Vh, 0, kh0, kh1, vh0, vh1);
  stl(arenaH, kh0, kh1, vh0, vh1);
  ldg(Km, Vm, 0, km0, km1, vm0, vm1);
  stl(arenaM, km0, km1, vm0, vm1);
  ldg(Kh, Vh, 1, kh0, kh1, vh0, vh1);
  ldg(Km, Vm, 1, km0, km1, vm0, vm1);

#pragma unroll 1
  for (int kc = 0; kc < 16; ++kc) {
    compute_both();                // all arena reads happen here
    if (kc < 15) {
      stl(arenaH, kh0, kh1, vh0, vh1);   // overwrite after reads (WAR-safe)
      stl(arenaM, km0, km1, vm0, vm1);
      if (kc < 14) {
        ldg(Kh, Vh, kc + 2, kh0, kh1, vh0, vh1);
        ldg(Km, Vm, kc + 2, km0, km1, vm0, vm1);
      }
    }
  }

  // all waves done with arenas before zcb overlay
  __syncthreads();

  // combine each branch into zp[query][br*64 + c]; zcb overlays arenas
  u16* const zcb = pool;
  auto combine = [&](int br, f32x4 (&z)[2][4], float (&rp)[2]) {
#pragma unroll
    for (int qt = 0; qt < 2; ++qt) {
      float v = rp[qt];
      v += __shfl_xor(v, 16);
      v += __shfl_xor(v, 32);
      if (q == 0) rsw[w][qt * 16 + mm] = v;
#pragma unroll
      for (int ct = 0; ct < 4; ++ct) {
        uint2 val;
        val.x = packbf_t(z[qt][ct][1], z[qt][ct][0]);
        val.y = packbf_t(z[qt][ct][3], z[qt][ct][2]);
        *(uint2*)(zcb + w * 2176 + (qt * 16 + mm) * 68 + ct * 16 + q * 4) = val;
      }
    }
    __syncthreads();
    const int c2 = tid & 31, qr = tid >> 5;
#pragma unroll
    for (int i = 0; i < 4; ++i) {
      const int query = qr + i * 8;
      const float rt = rsw[0][query] + rsw[1][query] + rsw[2][query] + rsw[3][query];
      const float rinv = __builtin_amdgcn_rcpf(rt);
      float vlo = 0.f, vhi = 0.f;
#pragma unroll
      for (int ww = 0; ww < 4; ++ww) {
        const u32 u = *(const u32*)(zcb + ww * 2176 + query * 68 + c2 * 2);
        vlo += __uint_as_float(u << 16);
        vhi += __uint_as_float(u & 0xffff0000u);
      }
      vlo *= rinv;
      vhi *= rinv;
      *(u32*)&zp[query][br * 64 + c2 * 2] = packbf_t(vhi, vlo);
    }
    __syncthreads();
  };
  combine(0, zA, rpA);
  combine(1, zB, rpB);

  // ---- tail phase A: Zp2 = Wz @ [Zh;Zm] + bz. zp2 overlays dead zcb/arenas.
  const int pxt = w & 1, oh = w >> 1;
  u16* const zp2 = pool;
  {
    bf16x8 za[4];
#pragma unroll
    for (int ks = 0; ks < 4; ++ks)
      za[ks] = *(const bf16x8*)&zp[pxt * 16 + mm][ks * 32 + q * 8];
#pragma unroll
    for (int ot = 0; ot < 4; ++ot) {
      const int o0 = oh * 64 + ot * 16;
      const float4 b4 = *(const float4*)(bz + o0 + q * 4);
      f32x4 d = {b4.x, b4.y, b4.z, b4.w};
#pragma unroll
      for (int ks = 0; ks < 4; ++ks) {
        const bf16x8 wb = *(const bf16x8*)(Wzb + (o0 + mm) * 128 + ks * 32 + q * 8);
        d = MFMA(wb, za[ks], d);
      }
      uint2 val;
      val.x = packbf(d[0], d[1]);
      val.y = packbf(d[2], d[3]);
      *(uint2*)(zp2 + (pxt * 16 + mm) * 136 + o0 + q * 4) = val;
    }
  }
  __syncthreads();

  // ---- tail phase B: combined = Wm @ [Zp2; h] + bm (gate-major, pre-scaled
  // by log2e / 2*log2e), gates via bare 2^x.
  {
    const int hb2 = oh;
    bf16x8 fa[6];
#pragma unroll
    for (int ks = 0; ks < 4; ++ks)
      fa[ks] = *(const bf16x8*)(zp2 + (pxt * 16 + mm) * 136 + ks * 32 + q * 8);
    {
      const u16* hp = hbuf + (b * 1024 + q0 + pxt * 16 + mm) * 64;
      fa[4] = *(const bf16x8*)(hp + q * 8);
      fa[5] = *(const bf16x8*)(hp + 32 + q * 8);
    }
    f32x4 dd[6];
#pragma unroll
    for (int j = 0; j < 6; ++j) {
      const int p = hb2 * 96 + j * 16 + mm;
      const float bb = bmp[p];
      f32x4 d = {bb, bb, bb, bb};
#pragma unroll
      for (int ks = 0; ks < 6; ++ks) {
        const bf16x8 wb = *(const bf16x8*)(Wmb + p * 192 + ks * 32 + q * 8);
        d = MFMA(fa[ks], wb, d);
      }
      dd[j] = d;
    }
#pragma unroll
    for (int ctl = 0; ctl < 2; ++ctl) {
      const int c = (hb2 * 2 + ctl) * 16 + mm;
      const int px = q0 + pxt * 16 + q * 4;
      const float4 mold = *(const float4*)(m_ + (b * 64 + c) * 1024 + px);
      float4 nh, nm;
#pragma unroll
      for (int r = 0; r < 4; ++r) {
        const float xo = dd[ctl * 3 + 0][r];   // pre-scaled by log2e
        const float xg = dd[ctl * 3 + 1][r];   // pre-scaled by 2*log2e
        const float xi = dd[ctl * 3 + 2][r];   // pre-scaled by log2e
        const float si = __builtin_amdgcn_rcpf(1.f + ex2(-xi));
        const float th = 1.f - 2.f * __builtin_amdgcn_rcpf(ex2(xg) + 1.f);
        const float so = __builtin_amdgcn_rcpf(1.f + ex2(-xo));
        const float mo = ((const float*)&mold)[r];
        const float nmv = (1.f - si) * mo + si * th;
        ((float*)&nm)[r] = nmv;
        ((float*)&nh)[r] = so * nmv;
      }
      *(float4*)(out + (b * 64 + c) * 1024 + px) = nh;
      *(float4*)(out + 1048576 + (b * 64 + c) * 1024 + px) = nm;
    }
  }
}

// ---------------------------------------------------------------------------
extern "C" void kernel_launch(void* const* d_in, const int* in_sizes, int n_in,
                              void* d_out, int out_size, void* d_ws, size_t ws_size,
                              hipStream_t stream) {
  const float* h   = (const float*)d_in[0];
  const float* m   = (const float*)d_in[1];
  const float* Wq  = (const float*)d_in[2];
  const float* bq  = (const float*)d_in[3];
  const float* Wk  = (const float*)d_in[4];
  const float* bk  = (const float*)d_in[5];
  const float* Wk2 = (const float*)d_in[6];
  const float* bk2 = (const float*)d_in[7];
  const float* Wv  = (const float*)d_in[8];
  const float* bv  = (const float*)d_in[9];
  const float* Wv2 = (const float*)d_in[10];
  const float* bv2 = (const float*)d_in[11];
  const float* Wz  = (const float*)d_in[12];
  const float* bz  = (const float*)d_in[13];
  const float* Wm  = (const float*)d_in[14];
  const float* bm  = (const float*)d_in[15];
  float* out = (float*)d_out;

  char* ws = (char*)d_ws;
  const size_t MB = 1024 * 1024;
  u16* Qb   = (u16*)(ws + 0 * MB);       // (B,N,64), pre-scaled by log2e
  u16* Khb  = (u16*)(ws + 2 * MB);
  u16* Kmb  = (u16*)(ws + 4 * MB);
  u16* Vhb  = (u16*)(ws + 6 * MB);       // blocked (b,kc,kw,c,16)
  u16* Vmb  = (u16*)(ws + 8 * MB);
  u16* hbuf = (u16*)(ws + 10 * MB);      // (B,N,64)
  u16* Wzb  = (u16*)(ws + 16 * MB + 40960);       // 128x128
  u16* Wmb  = (u16*)(ws + 16 * MB + 73728);       // 192x192 permuted+scaled
  float* bmp = (float*)(ws + 16 * MB + 147456);   // 192 permuted+scaled

  proj_kernel<<<dim3(16, 16, 5), 256, 0, stream>>>(
      h, m, bq, bk, bk2, bv, bv2, Wq, Wk, Wk2, Wv, Wv2, Wz, Wm, bm,
      Qb, Khb, Kmb, Vhb, Vmb, hbuf, Wzb, Wmb, bmp);
  attn_tail_kernel<<<512, 256, 0, stream>>>(Qb, Khb, Kmb, Vhb, Vmb, hbuf, m,
                                            Wzb, bz, Wmb, bmp, out);
}

// Round 16
// 133.369 us; speedup vs baseline: 1.0127x; 1.0127x over previous
//
#include <hip/hip_runtime.h>

typedef unsigned short u16;
typedef unsigned int u32;
typedef __attribute__((ext_vector_type(8))) short bf16x8;
typedef __attribute__((ext_vector_type(4))) short bf16x4;
typedef __attribute__((ext_vector_type(4))) float f32x4;

#define MFMA(a, b, c) __builtin_amdgcn_mfma_f32_16x16x32_bf16((a), (b), (c), 0, 0, 0)
#define MFMA16(a, b, c) __builtin_amdgcn_mfma_f32_16x16x16bf16_1k((a), (b), (c), 0, 0, 0)

// round-to-nearest-even f32 -> bf16
static __device__ __forceinline__ u16 f2bf(float x) {
  u32 u = __float_as_uint(x);
  u += 0x7FFFu + ((u >> 16) & 1u);
  return (u16)(u >> 16);
}
// pack two f32 -> (bf16(hi)<<16)|bf16(lo), truncating (hot paths)
static __device__ __forceinline__ u32 packbf_t(float hi, float lo) {
  return __builtin_amdgcn_perm(__float_as_uint(hi), __float_as_uint(lo), 0x07060302u);
}
// rounded pack: lo | hi<<16
static __device__ __forceinline__ u32 packbf(float lo, float hi) {
  return (u32)f2bf(lo) | ((u32)f2bf(hi) << 16);
}

// ---------------------------------------------------------------------------
// Kernel 1: 1x1-conv projections, ONE projection per block (z 0..4):
// z0: Q + hbuf, z1: Kh, z2: Vh, z3: Km, z4: Vm. grid (16,16,5) = 1280 blocks.
// Inline f32->bf16 weight conversion (weights L2-broadcast). Folded
// tail-weight prep (Wzb/Wmb/bmp); ordering guaranteed by kernel boundary.
// Q/K: (B,N,64). V: BLOCKED (b, kc=n/64, kw=key16grp, c, key16).
// ---------------------------------------------------------------------------
__global__ __launch_bounds__(256) void proj_kernel(
    const float* __restrict__ h, const float* __restrict__ m_,
    const float* __restrict__ bq, const float* __restrict__ bk,
    const float* __restrict__ bk2, const float* __restrict__ bv,
    const float* __restrict__ bv2,
    const float* __restrict__ Wq, const float* __restrict__ Wk,
    const float* __restrict__ Wk2, const float* __restrict__ Wv,
    const float* __restrict__ Wv2,
    const float* __restrict__ Wz, const float* __restrict__ Wm,
    const float* __restrict__ bm,
    u16* __restrict__ Qb, u16* __restrict__ Khb, u16* __restrict__ Kmb,
    u16* __restrict__ Vhb, u16* __restrict__ Vmb, u16* __restrict__ hbuf,
    u16* __restrict__ Wzb, u16* __restrict__ Wmb, float* __restrict__ bmp)
{
  const int tid = threadIdx.x;
  const int b = blockIdx.y, n0 = blockIdx.x * 64, z = blockIdx.z;

  // ---- folded tail-weight prep (consumed by merged kernel, next launch)
  {
    const int gid = (blockIdx.z * 256 + blockIdx.y * 16 + blockIdx.x) * 256 + tid;
    if (gid < 16384) {
      Wzb[gid] = f2bf(Wz[gid]);
    } else if (gid < 53248) {
      const int e = gid - 16384;
      const int p = e / 192, k = e % 192;
      const int hb2 = p / 96, r1 = p % 96, ctl = r1 / 48, r2 = r1 % 48;
      const int g = r2 >> 4, mm = r2 & 15;
      const int o = g * 64 + (hb2 * 2 + ctl) * 16 + mm;
      Wmb[p * 192 + k] = f2bf(Wm[o * 192 + k]);
    } else if (gid < 53440) {
      const int p = gid - 53248;
      const int hb2 = p / 96, r1 = p % 96, ctl = r1 / 48, r2 = r1 % 48;
      const int g = r2 >> 4, mm = r2 & 15;
      const int o = g * 64 + (hb2 * 2 + ctl) * 16 + mm;
      bmp[p] = bm[o];
    }
  }

  __shared__ __align__(16) u16 xt[64][72];  // [px][c] bf16
  const float* __restrict__ X = (z >= 3) ? m_ : h;

  {
    const int px = tid & 63, c0 = (tid >> 6) * 16;
#pragma unroll
    for (int i = 0; i < 8; ++i) {
      const int c = c0 + 2 * i;
      const float f0 = X[(b * 64 + c) * 1024 + n0 + px];
      const float f1 = X[(b * 64 + c + 1) * 1024 + n0 + px];
      *(u32*)&xt[px][c] = packbf(f0, f1);
    }
  }
  __syncthreads();

  const int lane = tid & 63, w = tid >> 6;  // w = 16-px tile
  const int mm = lane & 15, q = lane >> 4;

  const bf16x8 xa0 = *(const bf16x8*)&xt[w * 16 + mm][q * 8];
  const bf16x8 xa1 = *(const bf16x8*)&xt[w * 16 + mm][32 + q * 8];

  // load row `row` cols col0..col0+7 of a 64-wide f32 matrix, as bf16x8
  auto ldw8 = [&](const float* Wf, int row, int col0) {
    const float4 a = *(const float4*)(Wf + row * 64 + col0);
    const float4 bb = *(const float4*)(Wf + row * 64 + col0 + 4);
    union { u32 u[4]; bf16x8 v; } r;
    r.u[0] = packbf(a.x, a.y);
    r.u[1] = packbf(a.z, a.w);
    r.u[2] = packbf(bb.x, bb.y);
    r.u[3] = packbf(bb.z, bb.w);
    return r.v;
  };

  auto qk_store = [&](u16* dst, const float* Wf, const float* bias) {
#pragma unroll
    for (int ot = 0; ot < 4; ++ot) {
      const bf16x8 wb0 = ldw8(Wf, ot * 16 + mm, q * 8);
      const bf16x8 wb1 = ldw8(Wf, ot * 16 + mm, 32 + q * 8);
      const float4 b4 = *(const float4*)(bias + ot * 16 + q * 4);
      f32x4 d = {b4.x, b4.y, b4.z, b4.w};
      d = MFMA(wb0, xa0, d);
      d = MFMA(wb1, xa1, d);
      uint2 val;
      val.x = packbf(d[0], d[1]);
      val.y = packbf(d[2], d[3]);
      *(uint2*)(dst + (b * 1024 + n0 + w * 16 + mm) * 64 + ot * 16 + q * 4) = val;
    }
  };
  // V store, layout (b, kc, kw, c, k16): key = w*16 + (q*4+r)
  auto v_store = [&](u16* dst, const float* Wf, const float* bias) {
#pragma unroll
    for (int ot = 0; ot < 4; ++ot) {
      const bf16x8 wb0 = ldw8(Wf, ot * 16 + mm, q * 8);
      const bf16x8 wb1 = ldw8(Wf, ot * 16 + mm, 32 + q * 8);
      const float bb = bias[ot * 16 + mm];
      f32x4 d = {bb, bb, bb, bb};
      d = MFMA(xa0, wb0, d);
      d = MFMA(xa1, wb1, d);
      uint2 val;
      val.x = packbf(d[0], d[1]);
      val.y = packbf(d[2], d[3]);
      *(uint2*)(dst + b * 65536 + blockIdx.x * 4096 + w * 1024 +
                (ot * 16 + mm) * 16 + q * 4) = val;
    }
  };

  if (z == 0) {
    qk_store(Qb, Wq, bq);
    const int px = tid >> 2, sg = tid & 3;
    u32* dst = (u32*)(hbuf + (b * 1024 + n0 + px) * 64 + sg * 16);
    const u16* srcr = &xt[px][sg * 16];
#pragma unroll
    for (int j = 0; j < 8; ++j) dst[j] = *(const u32*)(srcr + 2 * j);
  } else if (z == 1) {
    qk_store(Khb, Wk, bk);
  } else if (z == 2) {
    v_store(Vhb, Wv, bv);
  } else if (z == 3) {
    qk_store(Kmb, Wk2, bk2);
  } else {
    v_store(Vmb, Wv2, bv2);
  }
}

// ---------------------------------------------------------------------------
// Kernel 2: MERGED attention + tail with DUAL-BRANCH INTERLEAVED loop.
// 512 blocks = 16 b (XCD-affine) x 32 query-groups of 32 queries; 2/CU.
// Both branches (h, m) advance through the SAME kc loop, giving the compiler
// two independent QK->exp->PV dependency chains per iteration to interleave
// (fills in-order-issue stall slots at 2 waves/SIMD). Per-wave LDS: two
// single-buffered arenas (H, M; 2688 u16 each). WAR-safe: same-wave DS ops
// execute in order, and the compiler cannot hoist maybe-aliasing stores
// above loads. Then combine -> zproj -> final -> gates.
// ---------------------------------------------------------------------------
__global__ __launch_bounds__(256) void attn_tail_kernel(
    const u16* __restrict__ Qb, const u16* __restrict__ Khb,
    const u16* __restrict__ Kmb, const u16* __restrict__ Vhb,
    const u16* __restrict__ Vmb, const u16* __restrict__ hbuf,
    const float* __restrict__ m_, const u16* __restrict__ Wzb,
    const float* __restrict__ bz, const u16* __restrict__ Wmb,
    const float* __restrict__ bmp, float* __restrict__ out)
{
  const int id = blockIdx.x;
  const int b = id & 15;            // batch -> fixed XCD
  const int qg = id >> 4;           // 0..31
  const int q0 = qg * 32;

  const u16* __restrict__ Kh = Khb + b * 65536;  // (N,64)
  const u16* __restrict__ Vh = Vhb + b * 65536;  // (kc,kw,c,16)
  const u16* __restrict__ Km = Kmb + b * 65536;
  const u16* __restrict__ Vm = Vmb + b * 65536;

  __shared__ __align__(16) u16 pool[21504];   // 4 wave-arenas / zcb / zp2
  __shared__ __align__(16) u16 zp[32][136];   // combined normalized Z tile
  __shared__ float rsw[4][32];

  const int tid = threadIdx.x, w = tid >> 6, lane = tid & 63;
  const int mm = lane & 15, q = lane >> 4;

  u16* const arenaH = pool + w * 5376;        // Kt 1152 + Vt 1536
  u16* const arenaM = arenaH + 2688;

  // Q B-operand frags for 2 query tiles: B[n=query=mm][k=d=q*8+j]
  bf16x8 qb0[2], qb1[2];
#pragma unroll
  for (int qt = 0; qt < 2; ++qt) {
    const u16* Qp = Qb + (b * 1024 + q0 + qt * 16 + mm) * 64;
    qb0[qt] = *(const bf16x8*)(Qp + q * 8);
    qb1[qt] = *(const bf16x8*)(Qp + 32 + q * 8);
  }

  f32x4 zA[2][4], zB[2][4];
  float rpA[2] = {0.f, 0.f}, rpB[2] = {0.f, 0.f};
#pragma unroll
  for (int qt = 0; qt < 2; ++qt)
#pragma unroll
    for (int ct = 0; ct < 4; ++ct) {
      zA[qt][ct] = (f32x4){0.f, 0.f, 0.f, 0.f};
      zB[qt][ct] = (f32x4){0.f, 0.f, 0.f, 0.f};
    }

  // per-wave staging: K slice (16 keys x 64d = 2KB) and V slice (64c x 16k =
  // 2KB) contiguous; each lane loads 32 B of each. Two live reg sets (H, M).
  uint4 kh0, kh1, vh0, vh1, km0, km1, vm0, vm1;
  auto ldg = [&](const u16* K, const u16* V, int kc, uint4& r0, uint4& r1,
                 uint4& s0, uint4& s1) {
    const u16* Ks = K + kc * 4096 + w * 1024 + lane * 16;
    const u16* Vs = V + kc * 4096 + w * 1024 + lane * 16;
    r0 = *(const uint4*)Ks;
    r1 = *(const uint4*)(Ks + 8);
    s0 = *(const uint4*)Vs;
    s1 = *(const uint4*)(Vs + 8);
  };
  auto stl = [&](u16* arena, const uint4& r0, const uint4& r1, const uint4& s0,
                 const uint4& s1) {
    u16* Kd = arena + (lane >> 2) * 72 + (lane & 3) * 16;
    u16* Vd = arena + 1152 + lane * 24;
    *(uint4*)Kd = r0;
    *(uint4*)(Kd + 8) = r1;
    *(uint4*)Vd = s0;
    *(uint4*)(Vd + 8) = s1;
  };

  auto compute = [&](const u16* arena, f32x4 (&z)[2][4], float (&rp)[2]) {
    const u16* Kt = arena;
    const u16* Vt = arena + 1152;
    const bf16x8 kf0 = *(const bf16x8*)(Kt + mm * 72 + q * 8);
    const bf16x8 kf1 = *(const bf16x8*)(Kt + mm * 72 + 32 + q * 8);
    bf16x4 vf[4];
#pragma unroll
    for (int ct = 0; ct < 4; ++ct)
      vf[ct] = *(const bf16x4*)(Vt + (ct * 16 + mm) * 24 + q * 4);

#pragma unroll
    for (int qt = 0; qt < 2; ++qt) {
      f32x4 s = {0.f, 0.f, 0.f, 0.f};
      s = MFMA(kf0, qb0[qt], s);
      s = MFMA(kf1, qb1[qt], s);
      const float e0 = __expf(s[0]), e1 = __expf(s[1]);
      const float e2 = __expf(s[2]), e3 = __expf(s[3]);
      rp[qt] += (e0 + e1) + (e2 + e3);
      union { u32 u[2]; bf16x4 v; } pb;
      pb.u[0] = packbf_t(e1, e0);   // B[k=q*4+{0,1}][n=mm]
      pb.u[1] = packbf_t(e3, e2);   // B[k=q*4+{2,3}][n=mm]
#pragma unroll
      for (int ct = 0; ct < 4; ++ct) z[qt][ct] = MFMA16(vf[ct], pb.v, z[qt][ct]);
    }
  };

  // prologue: chunk0 -> both arenas; regs hold chunk1 for both branches
  ldg(Kh, Vh, 0, kh0, kh1, vh0, vh1);
  stl(arenaH, kh0, kh1, vh0, vh1);
  ldg(Km, Vm, 0, km0, km1, vm0, vm1);
  stl(arenaM, km0, km1, vm0, vm1);
  ldg(Kh, Vh, 1, kh0, kh1, vh0, vh1);
  ldg(Km, Vm, 1, km0, km1, vm0, vm1);

#pragma unroll 1
  for (int kc = 0; kc < 16; ++kc) {
    // H branch: compute chunk kc (reads arenaH), then store chunk kc+1
    // (same-wave DS ordering makes read-then-overwrite safe), then issue
    // chunk kc+2 loads. M branch identical and fully independent -> the
    // scheduler interleaves the two chains.
    compute(arenaH, zA, rpA);
    if (kc < 15) {
      stl(arenaH, kh0, kh1, vh0, vh1);
      if (kc < 14) ldg(Kh, Vh, kc + 2, kh0, kh1, vh0, vh1);
    }
    compute(arenaM, zB, rpB);
    if (kc < 15) {
      stl(arenaM, km0, km1, vm0, vm1);
      if (kc < 14) ldg(Km, Vm, kc + 2, km0, km1, vm0, vm1);
    }
  }

  // all waves done with arenas before zcb overlay
  __syncthreads();

  // combine each branch into zp[query][br*64 + c]; zcb overlays arenas
  u16* const zcb = pool;
  auto combine = [&](int br, f32x4 (&z)[2][4], float (&rp)[2]) {
#pragma unroll
    for (int qt = 0; qt < 2; ++qt) {
      float v = rp[qt];
      v += __shfl_xor(v, 16);
      v += __shfl_xor(v, 32);
      if (q == 0) rsw[w][qt * 16 + mm] = v;
#pragma unroll
      for (int ct = 0; ct < 4; ++ct) {
        uint2 val;
        val.x = packbf_t(z[qt][ct][1], z[qt][ct][0]);
        val.y = packbf_t(z[qt][ct][3], z[qt][ct][2]);
        *(uint2*)(zcb + w * 2176 + (qt * 16 + mm) * 68 + ct * 16 + q * 4) = val;
      }
    }
    __syncthreads();
    const int c2 = tid & 31, qr = tid >> 5;
#pragma unroll
    for (int i = 0; i < 4; ++i) {
      const int query = qr + i * 8;
      const float rt = rsw[0][query] + rsw[1][query] + rsw[2][query] + rsw[3][query];
      const float rinv = __builtin_amdgcn_rcpf(rt);
      float vlo = 0.f, vhi = 0.f;
#pragma unroll
      for (int ww = 0; ww < 4; ++ww) {
        const u32 u = *(const u32*)(zcb + ww * 2176 + query * 68 + c2 * 2);
        vlo += __uint_as_float(u << 16);
        vhi += __uint_as_float(u & 0xffff0000u);
      }
      vlo *= rinv;
      vhi *= rinv;
      *(u32*)&zp[query][br * 64 + c2 * 2] = packbf_t(vhi, vlo);
    }
    __syncthreads();
  };
  combine(0, zA, rpA);
  combine(1, zB, rpB);

  // ---- tail phase A: Zp2 = Wz @ [Zh;Zm] + bz. zp2 overlays dead zcb/arenas.
  const int pxt = w & 1, oh = w >> 1;
  u16* const zp2 = pool;
  {
    bf16x8 za[4];
#pragma unroll
    for (int ks = 0; ks < 4; ++ks)
      za[ks] = *(const bf16x8*)&zp[pxt * 16 + mm][ks * 32 + q * 8];
#pragma unroll
    for (int ot = 0; ot < 4; ++ot) {
      const int o0 = oh * 64 + ot * 16;
      const float4 b4 = *(const float4*)(bz + o0 + q * 4);
      f32x4 d = {b4.x, b4.y, b4.z, b4.w};
#pragma unroll
      for (int ks = 0; ks < 4; ++ks) {
        const bf16x8 wb = *(const bf16x8*)(Wzb + (o0 + mm) * 128 + ks * 32 + q * 8);
        d = MFMA(wb, za[ks], d);
      }
      uint2 val;
      val.x = packbf(d[0], d[1]);
      val.y = packbf(d[2], d[3]);
      *(uint2*)(zp2 + (pxt * 16 + mm) * 136 + o0 + q * 4) = val;
    }
  }
  __syncthreads();

  // ---- tail phase B: combined = Wm @ [Zp2; h] + bm (gate-major rows), gates
  {
    const int hb2 = oh;
    bf16x8 fa[6];
#pragma unroll
    for (int ks = 0; ks < 4; ++ks)
      fa[ks] = *(const bf16x8*)(zp2 + (pxt * 16 + mm) * 136 + ks * 32 + q * 8);
    {
      const u16* hp = hbuf + (b * 1024 + q0 + pxt * 16 + mm) * 64;
      fa[4] = *(const bf16x8*)(hp + q * 8);
      fa[5] = *(const bf16x8*)(hp + 32 + q * 8);
    }
    f32x4 dd[6];
#pragma unroll
    for (int j = 0; j < 6; ++j) {
      const int p = hb2 * 96 + j * 16 + mm;
      const float bb = bmp[p];
      f32x4 d = {bb, bb, bb, bb};
#pragma unroll
      for (int ks = 0; ks < 6; ++ks) {
        const bf16x8 wb = *(const bf16x8*)(Wmb + p * 192 + ks * 32 + q * 8);
        d = MFMA(fa[ks], wb, d);
      }
      dd[j] = d;
    }
#pragma unroll
    for (int ctl = 0; ctl < 2; ++ctl) {
      const int c = (hb2 * 2 + ctl) * 16 + mm;
      const int px = q0 + pxt * 16 + q * 4;
      const float4 mold = *(const float4*)(m_ + (b * 64 + c) * 1024 + px);
      float4 nh, nm;
#pragma unroll
      for (int r = 0; r < 4; ++r) {
        const float xo = dd[ctl * 3 + 0][r];
        const float xg = dd[ctl * 3 + 1][r];
        const float xi = dd[ctl * 3 + 2][r];
        const float si = __builtin_amdgcn_rcpf(1.f + __expf(-xi));
        const float th = 1.f - 2.f * __builtin_amdgcn_rcpf(__expf(2.f * xg) + 1.f);
        const float so = __builtin_amdgcn_rcpf(1.f + __expf(-xo));
        const float mo = ((const float*)&mold)[r];
        const float nmv = (1.f - si) * mo + si * th;
        ((float*)&nm)[r] = nmv;
        ((float*)&nh)[r] = so * nmv;
      }
      *(float4*)(out + (b * 64 + c) * 1024 + px) = nh;
      *(float4*)(out + 1048576 + (b * 64 + c) * 1024 + px) = nm;
    }
  }
}

// ---------------------------------------------------------------------------
extern "C" void kernel_launch(void* const* d_in, const int* in_sizes, int n_in,
                              void* d_out, int out_size, void* d_ws, size_t ws_size,
                              hipStream_t stream) {
  const float* h   = (const float*)d_in[0];
  const float* m   = (const float*)d_in[1];
  const float* Wq  = (const float*)d_in[2];
  const float* bq  = (const float*)d_in[3];
  const float* Wk  = (const float*)d_in[4];
  const float* bk  = (const float*)d_in[5];
  const float* Wk2 = (const float*)d_in[6];
  const float* bk2 = (const float*)d_in[7];
  const float* Wv  = (const float*)d_in[8];
  const float* bv  = (const float*)d_in[9];
  const float* Wv2 = (const float*)d_in[10];
  const float* bv2 = (const float*)d_in[11];
  const float* Wz  = (const float*)d_in[12];
  const float* bz  = (const float*)d_in[13];
  const float* Wm  = (const float*)d_in[14];
  const float* bm  = (const float*)d_in[15];
  float* out = (float*)d_out;

  char* ws = (char*)d_ws;
  const size_t MB = 1024 * 1024;
  u16* Qb   = (u16*)(ws + 0 * MB);       // (B,N,64)
  u16* Khb  = (u16*)(ws + 2 * MB);
  u16* Kmb  = (u16*)(ws + 4 * MB);
  u16* Vhb  = (u16*)(ws + 6 * MB);       // blocked (b,kc,kw,c,16)
  u16* Vmb  = (u16*)(ws + 8 * MB);
  u16* hbuf = (u16*)(ws + 10 * MB);      // (B,N,64)
  u16* Wzb  = (u16*)(ws + 16 * MB + 40960);       // 128x128
  u16* Wmb  = (u16*)(ws + 16 * MB + 73728);       // 192x192 permuted
  float* bmp = (float*)(ws + 16 * MB + 147456);   // 192 permuted

  proj_kernel<<<dim3(16, 16, 5), 256, 0, stream>>>(
      h, m, bq, bk, bk2, bv, bv2, Wq, Wk, Wk2, Wv, Wv2, Wz, Wm, bm,
      Qb, Khb, Kmb, Vhb, Vmb, hbuf, Wzb, Wmb, bmp);
  attn_tail_kernel<<<512, 256, 0, stream>>>(Qb, Khb, Kmb, Vhb, Vmb, hbuf, m,
                                            Wzb, bz, Wmb, bmp, out);
}